// Round 10
// baseline (173.705 us; speedup 1.0000x reference)
//
#include <hip/hip_runtime.h>

#define NN 512
#define DD 64
#define TOPK 20
#define BB 128

// =============== K1: ALL input-independent work in ONE launch ==================
// (byte-identical to Round-9 passing kernel, plus counter zero)
__global__ __launch_bounds__(256) void k1_pre(const float* __restrict__ data,
                                              const float* __restrict__ emb,
                                              const float* __restrict__ fc_w,
                                              const float* __restrict__ fc_b,
                                              const float* __restrict__ attn_w,
                                              float* __restrict__ es_src,
                                              float* __restrict__ es_dst,
                                              double* __restrict__ gstats,
                                              float* __restrict__ z,
                                              float* __restrict__ zsrc,
                                              float* __restrict__ zdst,
                                              int* __restrict__ topk,
                                              int* __restrict__ counter) {
    __shared__ __align__(16) char smem[34816];
    const int bid = blockIdx.x, t = threadIdx.x;

    if (bid < 512) {
        // ---------------- ksel: f32 dots + bitonic top-20 ----------------------
        const int i = bid;
        unsigned long long* keys = (unsigned long long*)smem;   // 512 u64 = 4 KB
        float* Arow = (float*)(smem + 4096);                    // 64 f32
        const float4* e4 = (const float4*)emb;

        if (t < 64) Arow[t] = emb[i * 64 + t];
        __syncthreads();

        #pragma unroll
        for (int jj = 0; jj < 2; ++jj) {
            const int j = jj * 256 + t;
            float dot = 0.f, ss = 0.f;
            #pragma unroll
            for (int c = 0; c < 16; ++c) {
                const float4 b = e4[j * 16 + c];
                const float4 a = *(const float4*)&Arow[c * 4];
                dot += a.x * b.x; dot += a.y * b.y; dot += a.z * b.z; dot += a.w * b.w;
                ss  += b.x * b.x; ss  += b.y * b.y; ss  += b.z * b.z; ss  += b.w * b.w;
            }
            const float v = dot / sqrtf(ss);
            unsigned u = __float_as_uint(v);
            u ^= (u >> 31) ? 0xFFFFFFFFu : 0x80000000u;        // monotonic f32->u32
            keys[j] = ((unsigned long long)u << 32) | (unsigned)(~j);
        }
        __syncthreads();

        // bitonic sort ASCENDING (45 stages, 256 pairs/stage, all threads)
        for (int size = 2; size <= 512; size <<= 1) {
            for (int stride = size >> 1; stride > 0; stride >>= 1) {
                const int lo = ((t & ~(stride - 1)) << 1) | (t & (stride - 1));
                const int hi = lo + stride;
                const bool up = ((lo & size) == 0);
                const unsigned long long a = keys[lo], b2 = keys[hi];
                if ((a > b2) == up) { keys[lo] = b2; keys[hi] = a; }
                __syncthreads();
            }
        }

        if (t < TOPK) {
            const unsigned lo32 = (unsigned)keys[511 - t];
            topk[i * TOPK + t] = (int)(~lo32);
        }
    } else if (bid < 1536) {
        // ---------------- GEMM 64x64 tile, float4 LDS (bit-identical) ----------
        float (*As)[68]  = (float(*)[68])smem;             // 17408 B
        float (*WsT)[68] = (float(*)[68])(smem + 17408);   // 17408 B
        const long r0 = (long)(bid - 512) * 64;
        const float4* data4 = (const float4*)data;
        const float4* fcw4  = (const float4*)fc_w;

        for (int m = t; m < 1024; m += 256) {
            const int r = m >> 4, c4 = m & 15;
            *(float4*)&As[r][c4 * 4] = data4[(r0 + r) * 16 + c4];
        }
        for (int m = t; m < 1024; m += 256) {
            const int d = m >> 4, f4 = m & 15;
            float4 v = fcw4[d * 16 + f4];
            WsT[f4 * 4 + 0][d] = v.x;
            WsT[f4 * 4 + 1][d] = v.y;
            WsT[f4 * 4 + 2][d] = v.z;
            WsT[f4 * 4 + 3][d] = v.w;
        }
        __syncthreads();

        const int tr = t >> 4, tc = t & 15;
        float acc[4][4] = {};
        for (int k0 = 0; k0 < 64; k0 += 4) {
            float4 a4[4], b4[4];
            #pragma unroll
            for (int i = 0; i < 4; ++i) a4[i] = *(float4*)&As[tr * 4 + i][k0];
            #pragma unroll
            for (int kk = 0; kk < 4; ++kk) b4[kk] = *(float4*)&WsT[k0 + kk][tc * 4];
            #pragma unroll
            for (int i = 0; i < 4; ++i) {
                acc[i][0] += a4[i].x * b4[0].x + a4[i].y * b4[1].x + a4[i].z * b4[2].x + a4[i].w * b4[3].x;
                acc[i][1] += a4[i].x * b4[0].y + a4[i].y * b4[1].y + a4[i].z * b4[2].y + a4[i].w * b4[3].y;
                acc[i][2] += a4[i].x * b4[0].z + a4[i].y * b4[1].z + a4[i].z * b4[2].z + a4[i].w * b4[3].z;
                acc[i][3] += a4[i].x * b4[0].w + a4[i].y * b4[1].w + a4[i].z * b4[2].w + a4[i].w * b4[3].w;
            }
        }
        float bias[4], aw0[4], aw2[4];
        #pragma unroll
        for (int j = 0; j < 4; ++j) {
            bias[j] = fc_b[tc * 4 + j];
            aw0[j]  = attn_w[tc * 4 + j];
            aw2[j]  = attn_w[128 + tc * 4 + j];
        }
        float zb[4][4];
        #pragma unroll
        for (int i = 0; i < 4; ++i) {
            #pragma unroll
            for (int j = 0; j < 4; ++j) zb[i][j] = acc[i][j] + bias[j];
            float4 vv; vv.x = zb[i][0]; vv.y = zb[i][1]; vv.z = zb[i][2]; vv.w = zb[i][3];
            *(float4*)&z[(r0 + tr * 4 + i) * 64 + tc * 4] = vv;
        }
        __syncthreads();   // all As/WsT reads done -> safe to alias

        float (*redA)[17] = (float(*)[17])smem;            // aliases As
        float (*redB)[17] = (float(*)[17])(smem + 4352);
        #pragma unroll
        for (int i = 0; i < 4; ++i) {
            redA[tr * 4 + i][tc] = zb[i][0] * aw0[0] + zb[i][1] * aw0[1] + zb[i][2] * aw0[2] + zb[i][3] * aw0[3];
            redB[tr * 4 + i][tc] = zb[i][0] * aw2[0] + zb[i][1] * aw2[1] + zb[i][2] * aw2[2] + zb[i][3] * aw2[3];
        }
        __syncthreads();
        if (t < 64) {
            float sA = 0.f, sB = 0.f;
            #pragma unroll
            for (int k = 0; k < 16; ++k) { sA += redA[t][k]; sB += redB[t][k]; }
            zsrc[r0 + t] = sA;
            zdst[r0 + t] = sB;
        }
    } else {
        // ---------------- es_src / es_dst + gstats/counter zero ----------------
        #pragma unroll
        for (int jj = 0; jj < 2; ++jj) {
            const int j = jj * 256 + t;
            float s1 = 0.f, s2 = 0.f;
            #pragma unroll
            for (int c = 0; c < 64; ++c) {
                const float w = emb[j * 64 + c];
                s1 += w * attn_w[64 + c];
                s2 += w * attn_w[192 + c];
            }
            es_src[j] = s1;
            es_dst[j] = s2;
        }
        if (t < 128) gstats[t] = 0.0;
        if (t == 128) *counter = 0;
    }
}

// =============== K3: attention + BN atomics + FUSED k5 (producer-exit spin) ====
// Phase A/B byte-identical to Round-9. Then: every block fences + counts;
// dq!=0 blocks EXIT (so unlaunched blocks can always start -> deadlock-free);
// the 128 dq==0 blocks spin on the counter via atomic-RMW reads (coherence-
// point reads; a plain load could spin on a stale non-coherent L2 line),
// acquire-fence, then run k5's exact math for their batch's 512 rows.
__global__ __launch_bounds__(256) void k3_attn(const float* __restrict__ z,
                                               const float* __restrict__ zsrc,
                                               const float* __restrict__ zdst,
                                               const float* __restrict__ es_src,
                                               const float* __restrict__ es_dst,
                                               const int* __restrict__ topk,
                                               const float* __restrict__ emb,
                                               const float* __restrict__ attn_b_p,
                                               float* __restrict__ rst,
                                               double* __restrict__ gstats,
                                               int* __restrict__ counter,
                                               const float* __restrict__ gamma,
                                               const float* __restrict__ beta,
                                               const float* __restrict__ out_w,
                                               const float* __restrict__ out_b_p,
                                               float* __restrict__ out) {
    __shared__ float  zs[512 * 20];          // 40 KB (rows: 5 float4, slot 4 = pad)
    __shared__ double alf_pool[2560];        // 20 KB: alpha[256][20] / BN-reduce alias
    __shared__ unsigned short sIdx[256 * 20];// 10 KB; scv/biv alias in phase C
    float* alf = (float*)alf_pool;
    const float4* alf4 = (const float4*)alf_pool;   // rows are 80 B = 5 float4

    const int b    = blockIdx.x >> 2;
    const int dq   = blockIdx.x & 3;
    const int doff = dq * 16;
    const int t    = threadIdx.x;
    const float attn_b = *attn_b_p;
    const long b512 = (long)b * NN;

    float4* zs4 = (float4*)zs;
    for (int m = t; m < 2048; m += 256) {
        const int n = m >> 2, c4i = m & 3;
        zs4[n * 5 + c4i] = *(const float4*)(z + (b512 + n) * 64 + doff + c4i * 4);
    }
    __syncthreads();

    const int c4 = t & 3;
    const int rq = t >> 2;
    double s1[4] = {0,0,0,0}, s2[4] = {0,0,0,0};

    for (int chunk = 0; chunk < 2; ++chunk) {
        {
            const int n = chunk * 256 + t;
            const float sd = zdst[b512 + n] + es_dst[n] + attn_b;
            float ev[TOPK];
            float m0 = -1e30f;
            #pragma unroll
            for (int tt = 0; tt < TOPK; ++tt) {
                const int s = topk[n + tt * NN];   // scrambled flat edge list
                sIdx[t * TOPK + tt] = (unsigned short)s;
                float e = zsrc[b512 + s] + es_src[s] + sd;
                e = (e >= 0.f) ? e : 0.2f * e;
                ev[tt] = e;
                m0 = fmaxf(m0, e);
            }
            float dsum = 0.f;
            #pragma unroll
            for (int tt = 0; tt < TOPK; ++tt) { ev[tt] = __expf(ev[tt] - m0); dsum += ev[tt]; }
            const float inv = 1.0f / dsum;
            #pragma unroll
            for (int tt = 0; tt < TOPK; ++tt) alf[t * TOPK + tt] = ev[tt] * inv;
        }
        __syncthreads();

        #pragma unroll
        for (int it = 0; it < 4; ++it) {
            const int nl = it * 64 + rq;
            const int n  = chunk * 256 + nl;
            float4 af[5];
            #pragma unroll
            for (int q = 0; q < 5; ++q) af[q] = alf4[nl * 5 + q];
            const float* av = (const float*)af;
            float4 acc = {0.f, 0.f, 0.f, 0.f};
            #pragma unroll
            for (int tt = 0; tt < TOPK; ++tt) {
                const float a = av[tt];
                const float4 zv = zs4[(int)sIdx[nl * TOPK + tt] * 5 + c4];
                acc.x += a * zv.x; acc.y += a * zv.y; acc.z += a * zv.z; acc.w += a * zv.w;
            }
            const float4 ev = *(const float4*)&emb[n * 64 + doff + c4 * 4];
            float4 r;
            r.x = acc.x * ev.x; r.y = acc.y * ev.y; r.z = acc.z * ev.z; r.w = acc.w * ev.w;
            *(float4*)&rst[(b512 + n) * 64 + doff + c4 * 4] = r;
            s1[0] += (double)r.x; s2[0] += (double)r.x * (double)r.x;
            s1[1] += (double)r.y; s2[1] += (double)r.y * (double)r.y;
            s1[2] += (double)r.z; s2[2] += (double)r.z * (double)r.z;
            s1[3] += (double)r.w; s2[3] += (double)r.w * (double)r.w;
        }
        __syncthreads();
    }

    double* r1 = alf_pool;
    double* r2 = alf_pool + 1024;
    #pragma unroll
    for (int j = 0; j < 4; ++j) {
        r1[(c4 * 4 + j) * 64 + rq] = s1[j];
        r2[(c4 * 4 + j) * 64 + rq] = s2[j];
    }
    __syncthreads();
    if (t < 16) {
        double a = 0.0, bb = 0.0;
        for (int q = 0; q < 64; ++q) { a += r1[t * 64 + q]; bb += r2[t * 64 + q]; }
        atomicAdd(&gstats[doff + t], a);
        atomicAdd(&gstats[64 + doff + t], bb);
    }

    // ---- producer-exit spin barrier ------------------------------------------
    __syncthreads();                 // drains all waves' stores/atomics (vmcnt 0)
    if (t == 0) {
        __threadfence();             // release: rst stores + gstats visible device-wide
        atomicAdd(counter, 1);
    }
    if (dq != 0) return;             // producers exit -> stragglers can launch

    if (t == 0) {
        while (atomicAdd(counter, 0) < 512) __builtin_amdgcn_s_sleep(2);
        __threadfence();             // acquire
    }
    __syncthreads();

    // ---- fused K5 for batch b (512 rows), k5's exact math --------------------
    float* scv = (float*)sIdx;       // sIdx/zs/alf_pool all dead now
    float* biv = scv + 64;
    if (t < 64) {
        const double M = (double)BB * (double)NN;
        const double s   = gstats[t];
        const double s2g = gstats[64 + t];
        const double mu  = s / M;
        const double var = s2g / M - mu * mu;
        const float scale = (float)((double)gamma[t] / sqrt(var + 1e-5));
        scv[t] = scale;
        biv[t] = beta[t] - (float)mu * scale;
    }
    __syncthreads();

    const int wid = t >> 6, lane = t & 63;
    const float sc = scv[lane], bi = biv[lane], ow = out_w[lane];
    const float ob = *out_b_p;
    for (int rr0 = 0; rr0 < NN; rr0 += 16) {
        const long rowbase = b512 + rr0 + wid * 4;
        float v[4];
        #pragma unroll
        for (int rr = 0; rr < 4; ++rr)
            v[rr] = fmaxf(rst[(rowbase + rr) * 64 + lane] * sc + bi, 0.f) * ow;
        #pragma unroll
        for (int off = 32; off > 0; off >>= 1)
            #pragma unroll
            for (int rr = 0; rr < 4; ++rr) v[rr] += __shfl_down(v[rr], off);
        if (lane == 0)
            #pragma unroll
            for (int rr = 0; rr < 4; ++rr) out[rowbase + rr] = v[rr] + ob;
    }
}

extern "C" void kernel_launch(void* const* d_in, const int* in_sizes, int n_in,
                              void* d_out, int out_size, void* d_ws, size_t ws_size,
                              hipStream_t stream) {
    const float* data   = (const float*)d_in[0];
    const float* emb    = (const float*)d_in[1];
    const float* fc_w   = (const float*)d_in[2];
    const float* fc_b   = (const float*)d_in[3];
    const float* attn_w = (const float*)d_in[4];
    const float* attn_b = (const float*)d_in[5];
    const float* gamma  = (const float*)d_in[6];
    const float* beta   = (const float*)d_in[7];
    const float* out_w  = (const float*)d_in[8];
    const float* out_b  = (const float*)d_in[9];
    float* out = (float*)d_out;

    char* ws = (char*)d_ws;
    float*  z      = (float*) (ws + 0);            // 16 MB
    float*  rst    = (float*) (ws + 16777216);     // 16 MB
    float*  zsrc   = (float*) (ws + 33554432);     // 256 KB
    float*  zdst   = (float*) (ws + 33816576);     // 256 KB
    int*    topk   = (int*)   (ws + 34078720);     // 40 KB
    float*  es_src = (float*) (ws + 34119680);     // 2 KB
    float*  es_dst = (float*) (ws + 34121728);     // 2 KB
    double* gstats = (double*)(ws + 34123776);     // 1 KB
    int*    counter= (int*)   (ws + 34124800);     // 4 B

    k1_pre<<<1537, 256, 0, stream>>>(data, emb, fc_w, fc_b, attn_w,
                                     es_src, es_dst, gstats,
                                     z, zsrc, zdst, topk, counter);
    k3_attn<<<BB * 4, 256, 0, stream>>>(z, zsrc, zdst, es_src, es_dst, topk, emb,
                                        attn_b, rst, gstats, counter,
                                        gamma, beta, out_w, out_b, out);
}

// Round 11
// 133.785 us; speedup vs baseline: 1.2984x; 1.2984x over previous
//
#include <hip/hip_runtime.h>

#define NN 512
#define DD 64
#define TOPK 20
#define BB 128

// =============== K1: ALL input-independent work in ONE launch ==================
// blocks    0..511  : ksel — f32 ranking + bitonic-sort top-20
// blocks  512..1535 : z GEMM 64x64 tiles + zsrc/zdst epilogue
// block  1536       : es_src / es_dst + gstats zero
// (byte-identical to the Round-9 verified 135.6 µs kernel)
__global__ __launch_bounds__(256) void k1_pre(const float* __restrict__ data,
                                              const float* __restrict__ emb,
                                              const float* __restrict__ fc_w,
                                              const float* __restrict__ fc_b,
                                              const float* __restrict__ attn_w,
                                              float* __restrict__ es_src,
                                              float* __restrict__ es_dst,
                                              double* __restrict__ gstats,
                                              float* __restrict__ z,
                                              float* __restrict__ zsrc,
                                              float* __restrict__ zdst,
                                              int* __restrict__ topk) {
    __shared__ __align__(16) char smem[34816];
    const int bid = blockIdx.x, t = threadIdx.x;

    if (bid < 512) {
        // ---------------- ksel: f32 dots + bitonic top-20 ----------------------
        const int i = bid;
        unsigned long long* keys = (unsigned long long*)smem;   // 512 u64 = 4 KB
        float* Arow = (float*)(smem + 4096);                    // 64 f32
        const float4* e4 = (const float4*)emb;

        if (t < 64) Arow[t] = emb[i * 64 + t];
        __syncthreads();

        #pragma unroll
        for (int jj = 0; jj < 2; ++jj) {
            const int j = jj * 256 + t;
            float dot = 0.f, ss = 0.f;
            #pragma unroll
            for (int c = 0; c < 16; ++c) {
                const float4 b = e4[j * 16 + c];
                const float4 a = *(const float4*)&Arow[c * 4];
                dot += a.x * b.x; dot += a.y * b.y; dot += a.z * b.z; dot += a.w * b.w;
                ss  += b.x * b.x; ss  += b.y * b.y; ss  += b.z * b.z; ss  += b.w * b.w;
            }
            const float v = dot / sqrtf(ss);
            unsigned u = __float_as_uint(v);
            u ^= (u >> 31) ? 0xFFFFFFFFu : 0x80000000u;        // monotonic f32->u32
            keys[j] = ((unsigned long long)u << 32) | (unsigned)(~j);
        }
        __syncthreads();

        // bitonic sort ASCENDING (45 stages, 256 pairs/stage, all threads)
        for (int size = 2; size <= 512; size <<= 1) {
            for (int stride = size >> 1; stride > 0; stride >>= 1) {
                const int lo = ((t & ~(stride - 1)) << 1) | (t & (stride - 1));
                const int hi = lo + stride;
                const bool up = ((lo & size) == 0);
                const unsigned long long a = keys[lo], b2 = keys[hi];
                if ((a > b2) == up) { keys[lo] = b2; keys[hi] = a; }
                __syncthreads();
            }
        }

        if (t < TOPK) {
            const unsigned lo32 = (unsigned)keys[511 - t];
            topk[i * TOPK + t] = (int)(~lo32);
        }
    } else if (bid < 1536) {
        // ---------------- GEMM 64x64 tile, float4 LDS --------------------------
        float (*As)[68]  = (float(*)[68])smem;             // 17408 B
        float (*WsT)[68] = (float(*)[68])(smem + 17408);   // 17408 B
        const long r0 = (long)(bid - 512) * 64;
        const float4* data4 = (const float4*)data;
        const float4* fcw4  = (const float4*)fc_w;

        for (int m = t; m < 1024; m += 256) {
            const int r = m >> 4, c4 = m & 15;
            *(float4*)&As[r][c4 * 4] = data4[(r0 + r) * 16 + c4];
        }
        for (int m = t; m < 1024; m += 256) {
            const int d = m >> 4, f4 = m & 15;
            float4 v = fcw4[d * 16 + f4];
            WsT[f4 * 4 + 0][d] = v.x;
            WsT[f4 * 4 + 1][d] = v.y;
            WsT[f4 * 4 + 2][d] = v.z;
            WsT[f4 * 4 + 3][d] = v.w;
        }
        __syncthreads();

        const int tr = t >> 4, tc = t & 15;
        float acc[4][4] = {};
        for (int k0 = 0; k0 < 64; k0 += 4) {
            float4 a4[4], b4[4];
            #pragma unroll
            for (int i = 0; i < 4; ++i) a4[i] = *(float4*)&As[tr * 4 + i][k0];
            #pragma unroll
            for (int kk = 0; kk < 4; ++kk) b4[kk] = *(float4*)&WsT[k0 + kk][tc * 4];
            #pragma unroll
            for (int i = 0; i < 4; ++i) {
                acc[i][0] += a4[i].x * b4[0].x + a4[i].y * b4[1].x + a4[i].z * b4[2].x + a4[i].w * b4[3].x;
                acc[i][1] += a4[i].x * b4[0].y + a4[i].y * b4[1].y + a4[i].z * b4[2].y + a4[i].w * b4[3].y;
                acc[i][2] += a4[i].x * b4[0].z + a4[i].y * b4[1].z + a4[i].z * b4[2].z + a4[i].w * b4[3].z;
                acc[i][3] += a4[i].x * b4[0].w + a4[i].y * b4[1].w + a4[i].z * b4[2].w + a4[i].w * b4[3].w;
            }
        }
        float bias[4], aw0[4], aw2[4];
        #pragma unroll
        for (int j = 0; j < 4; ++j) {
            bias[j] = fc_b[tc * 4 + j];
            aw0[j]  = attn_w[tc * 4 + j];
            aw2[j]  = attn_w[128 + tc * 4 + j];
        }
        float zb[4][4];
        #pragma unroll
        for (int i = 0; i < 4; ++i) {
            #pragma unroll
            for (int j = 0; j < 4; ++j) zb[i][j] = acc[i][j] + bias[j];
            float4 vv; vv.x = zb[i][0]; vv.y = zb[i][1]; vv.z = zb[i][2]; vv.w = zb[i][3];
            *(float4*)&z[(r0 + tr * 4 + i) * 64 + tc * 4] = vv;
        }
        __syncthreads();   // all As/WsT reads done -> safe to alias

        float (*redA)[17] = (float(*)[17])smem;            // aliases As
        float (*redB)[17] = (float(*)[17])(smem + 4352);
        #pragma unroll
        for (int i = 0; i < 4; ++i) {
            redA[tr * 4 + i][tc] = zb[i][0] * aw0[0] + zb[i][1] * aw0[1] + zb[i][2] * aw0[2] + zb[i][3] * aw0[3];
            redB[tr * 4 + i][tc] = zb[i][0] * aw2[0] + zb[i][1] * aw2[1] + zb[i][2] * aw2[2] + zb[i][3] * aw2[3];
        }
        __syncthreads();
        if (t < 64) {
            float sA = 0.f, sB = 0.f;
            #pragma unroll
            for (int k = 0; k < 16; ++k) { sA += redA[t][k]; sB += redB[t][k]; }
            zsrc[r0 + t] = sA;
            zdst[r0 + t] = sB;
        }
    } else {
        // ---------------- es_src / es_dst + gstats zero ------------------------
        #pragma unroll
        for (int jj = 0; jj < 2; ++jj) {
            const int j = jj * 256 + t;
            float s1 = 0.f, s2 = 0.f;
            #pragma unroll
            for (int c = 0; c < 64; ++c) {
                const float w = emb[j * 64 + c];
                s1 += w * attn_w[64 + c];
                s2 += w * attn_w[192 + c];
            }
            es_src[j] = s1;
            es_dst[j] = s2;
        }
        if (t < 128) gstats[t] = 0.0;
    }
}

// =============== K3: verified structure, zs rows padded to 80 B ================
// (byte-identical to the Round-9 verified kernel)
__global__ __launch_bounds__(256) void k3_attn(const float* __restrict__ z,
                                               const float* __restrict__ zsrc,
                                               const float* __restrict__ zdst,
                                               const float* __restrict__ es_src,
                                               const float* __restrict__ es_dst,
                                               const int* __restrict__ topk,
                                               const float* __restrict__ emb,
                                               const float* __restrict__ attn_b_p,
                                               float* __restrict__ rst,
                                               double* __restrict__ gstats) {
    __shared__ float  zs[512 * 20];          // 40 KB (rows: 5 float4, slot 4 = pad)
    __shared__ double alf_pool[2560];        // 20 KB: alpha[256][20] / BN-reduce alias
    __shared__ unsigned short sIdx[256 * 20];// 10 KB
    float* alf = (float*)alf_pool;
    const float4* alf4 = (const float4*)alf_pool;   // rows are 80 B = 5 float4

    const int b    = blockIdx.x >> 2;
    const int dq   = blockIdx.x & 3;
    const int doff = dq * 16;
    const int t    = threadIdx.x;
    const float attn_b = *attn_b_p;
    const long b512 = (long)b * NN;

    float4* zs4 = (float4*)zs;
    for (int m = t; m < 2048; m += 256) {
        const int n = m >> 2, c4i = m & 3;
        zs4[n * 5 + c4i] = *(const float4*)(z + (b512 + n) * 64 + doff + c4i * 4);
    }
    __syncthreads();

    const int c4 = t & 3;
    const int rq = t >> 2;
    double s1[4] = {0,0,0,0}, s2[4] = {0,0,0,0};

    for (int chunk = 0; chunk < 2; ++chunk) {
        {
            const int n = chunk * 256 + t;
            const float sd = zdst[b512 + n] + es_dst[n] + attn_b;
            float ev[TOPK];
            float m0 = -1e30f;
            #pragma unroll
            for (int tt = 0; tt < TOPK; ++tt) {
                const int s = topk[n + tt * NN];   // scrambled flat edge list
                sIdx[t * TOPK + tt] = (unsigned short)s;
                float e = zsrc[b512 + s] + es_src[s] + sd;
                e = (e >= 0.f) ? e : 0.2f * e;
                ev[tt] = e;
                m0 = fmaxf(m0, e);
            }
            float dsum = 0.f;
            #pragma unroll
            for (int tt = 0; tt < TOPK; ++tt) { ev[tt] = __expf(ev[tt] - m0); dsum += ev[tt]; }
            const float inv = 1.0f / dsum;
            #pragma unroll
            for (int tt = 0; tt < TOPK; ++tt) alf[t * TOPK + tt] = ev[tt] * inv;
        }
        __syncthreads();

        #pragma unroll
        for (int it = 0; it < 4; ++it) {
            const int nl = it * 64 + rq;
            const int n  = chunk * 256 + nl;
            float4 af[5];
            #pragma unroll
            for (int q = 0; q < 5; ++q) af[q] = alf4[nl * 5 + q];
            const float* av = (const float*)af;
            float4 acc = {0.f, 0.f, 0.f, 0.f};
            #pragma unroll
            for (int tt = 0; tt < TOPK; ++tt) {
                const float a = av[tt];
                const float4 zv = zs4[(int)sIdx[nl * TOPK + tt] * 5 + c4];
                acc.x += a * zv.x; acc.y += a * zv.y; acc.z += a * zv.z; acc.w += a * zv.w;
            }
            const float4 ev = *(const float4*)&emb[n * 64 + doff + c4 * 4];
            float4 r;
            r.x = acc.x * ev.x; r.y = acc.y * ev.y; r.z = acc.z * ev.z; r.w = acc.w * ev.w;
            *(float4*)&rst[(b512 + n) * 64 + doff + c4 * 4] = r;
            s1[0] += (double)r.x; s2[0] += (double)r.x * (double)r.x;
            s1[1] += (double)r.y; s2[1] += (double)r.y * (double)r.y;
            s1[2] += (double)r.z; s2[2] += (double)r.z * (double)r.z;
            s1[3] += (double)r.w; s2[3] += (double)r.w * (double)r.w;
        }
        __syncthreads();
    }

    double* r1 = alf_pool;
    double* r2 = alf_pool + 1024;
    #pragma unroll
    for (int j = 0; j < 4; ++j) {
        r1[(c4 * 4 + j) * 64 + rq] = s1[j];
        r2[(c4 * 4 + j) * 64 + rq] = s2[j];
    }
    __syncthreads();
    if (t < 16) {
        double a = 0.0, bb = 0.0;
        for (int q = 0; q < 64; ++q) { a += r1[t * 64 + q]; bb += r2[t * 64 + q]; }
        atomicAdd(&gstats[doff + t], a);
        atomicAdd(&gstats[64 + doff + t], bb);
    }
}

// =============== K5: BN finalize (per-block) + apply + ReLU + out_w dot ========
// (byte-identical to the verified kernel)
__global__ __launch_bounds__(256) void k5_out(const float* __restrict__ rst,
                                              const double* __restrict__ gstats,
                                              const float* __restrict__ gamma,
                                              const float* __restrict__ beta,
                                              const float* __restrict__ out_w,
                                              const float* __restrict__ out_b_p,
                                              float* __restrict__ out) {
    __shared__ float scv[64], biv[64];
    const int t = threadIdx.x;
    if (t < 64) {
        const double M = (double)BB * (double)NN;
        const double s  = gstats[t];
        const double s2 = gstats[64 + t];
        const double mu  = s / M;
        const double var = s2 / M - mu * mu;
        const float scale = (float)((double)gamma[t] / sqrt(var + 1e-5));
        scv[t] = scale;
        biv[t] = beta[t] - (float)mu * scale;
    }
    __syncthreads();

    const int wid = t >> 6, lane = t & 63;
    const float sc = scv[lane], bi = biv[lane], ow = out_w[lane];
    const float ob = *out_b_p;
    const long rowbase = (long)blockIdx.x * 16 + wid * 4;
    float v[4];
    #pragma unroll
    for (int rr = 0; rr < 4; ++rr)
        v[rr] = fmaxf(rst[(rowbase + rr) * 64 + lane] * sc + bi, 0.f) * ow;
    #pragma unroll
    for (int off = 32; off > 0; off >>= 1)
        #pragma unroll
        for (int rr = 0; rr < 4; ++rr) v[rr] += __shfl_down(v[rr], off);
    if (lane == 0)
        #pragma unroll
        for (int rr = 0; rr < 4; ++rr) out[rowbase + rr] = v[rr] + ob;
}

extern "C" void kernel_launch(void* const* d_in, const int* in_sizes, int n_in,
                              void* d_out, int out_size, void* d_ws, size_t ws_size,
                              hipStream_t stream) {
    const float* data   = (const float*)d_in[0];
    const float* emb    = (const float*)d_in[1];
    const float* fc_w   = (const float*)d_in[2];
    const float* fc_b   = (const float*)d_in[3];
    const float* attn_w = (const float*)d_in[4];
    const float* attn_b = (const float*)d_in[5];
    const float* gamma  = (const float*)d_in[6];
    const float* beta   = (const float*)d_in[7];
    const float* out_w  = (const float*)d_in[8];
    const float* out_b  = (const float*)d_in[9];
    float* out = (float*)d_out;

    char* ws = (char*)d_ws;
    float*  z      = (float*) (ws + 0);            // 16 MB
    float*  rst    = (float*) (ws + 16777216);     // 16 MB
    float*  zsrc   = (float*) (ws + 33554432);     // 256 KB
    float*  zdst   = (float*) (ws + 33816576);     // 256 KB
    int*    topk   = (int*)   (ws + 34078720);     // 40 KB
    float*  es_src = (float*) (ws + 34119680);     // 2 KB
    float*  es_dst = (float*) (ws + 34121728);     // 2 KB
    double* gstats = (double*)(ws + 34123776);     // 1 KB

    k1_pre<<<1537, 256, 0, stream>>>(data, emb, fc_w, fc_b, attn_w,
                                     es_src, es_dst, gstats,
                                     z, zsrc, zdst, topk);
    k3_attn<<<BB * 4, 256, 0, stream>>>(z, zsrc, zdst, es_src, es_dst, topk, emb,
                                        attn_b, rst, gstats);
    k5_out<<<4096, 256, 0, stream>>>(rst, gstats, gamma, beta, out_w, out_b, out);
}